// Round 9
// baseline (50.024 us; speedup 1.0000x reference)
//
#include <hip/hip_runtime.h>
#include <hip/hip_cooperative_groups.h>
#include <math.h>

namespace cg = cooperative_groups;

static constexpr int Bb   = 16;
static constexpr int Ww   = 256;
static constexpr int HWp  = 256 * 256;   // 65536
static constexpr int CF   = 128;
static constexpr int Kk   = 2;
static constexpr int SEGS = 8;
static constexpr int SEGLEN = HWp / SEGS; // 8192
static constexpr int NBLK = 32 * SEGS;    // 256 blocks

// Strict total order matching jax.lax.top_k: value descending, index ascending on ties.
__device__ __forceinline__ bool better(float v1, int i1, float v2, int i2) {
    return (v1 > v2) || ((v1 == v2) && (i1 < i2));
}

// merge sorted pair (b0,b1) into sorted pair (a0,a1)
__device__ __forceinline__ void merge2(float& a0, int& ia0, float& a1, int& ia1,
                                       float b0, int ib0, float b1, int ib1) {
    if (better(b0, ib0, a0, ia0)) {
        float na1; int nia1;
        if (better(a0, ia0, b1, ib1)) { na1 = a0; nia1 = ia0; }
        else                          { na1 = b1; nia1 = ib1; }
        a0 = b0; ia0 = ib0; a1 = na1; ia1 = nia1;
    } else if (better(b0, ib0, a1, ia1)) {
        a1 = b0; ia1 = ib0;
    }
}

// Single cooperative kernel: Phase A = R8 stage-1 verbatim (one block per
// (row,seg)); grid.sync(); Phase B = R8 stage-2 verbatim on blocks 0..63.
__global__ __launch_bounds__(256) void genpixel_coop(
    const float* __restrict__ infeat,
    const float* __restrict__ labelTpesudo,
    const float* __restrict__ labelT,
    const float* __restrict__ FeatureDA,
    float* __restrict__ ws_v, int* __restrict__ ws_i,
    float* __restrict__ out)
{
    const int blk = blockIdx.x;        // 0..255
    const int row = blk >> 3;          // 0..31
    const int seg = blk & 7;           // 0..7
    const int b = row >> 1, c = row & 1;
    const int t = threadIdx.x;

    // ---------------- Phase A ----------------
    {
        const float* x0p = infeat + (size_t)(b * 2 + 0) * HWp;
        const float* x1p = infeat + (size_t)(b * 2 + 1) * HWp;

        float v0 = -INFINITY, v1 = -INFINITY;
        int   i0 = 0x7fffffff, i1 = 0x7fffffff;

        const int base = seg * SEGLEN + t * 4;
        #pragma unroll
        for (int it = 0; it < SEGLEN / (256 * 4); ++it) {
            const int p = base + it * (256 * 4);
            const float4 a  = *(const float4*)(x0p + p);
            const float4 bb = *(const float4*)(x1p + p);
            const float ax[4] = {a.x, a.y, a.z, a.w};
            const float bx[4] = {bb.x, bb.y, bb.z, bb.w};
            #pragma unroll
            for (int e = 0; e < 4; ++e) {
                const float m  = fmaxf(ax[e], bx[e]);
                const float e0 = expf(ax[e] - m);
                const float e1 = expf(bx[e] - m);
                const float v  = (c == 0 ? e0 : e1) / (e0 + e1);
                const int p2 = p + e;
                if (better(v, p2, v0, i0)) { v1 = v0; i1 = i0; v0 = v; i0 = p2; }
                else if (better(v, p2, v1, i1)) { v1 = v; i1 = p2; }
            }
        }

        // 64-lane in-register butterfly
        #pragma unroll
        for (int m = 1; m < 64; m <<= 1) {
            float o0 = __shfl_xor(v0, m), o1 = __shfl_xor(v1, m);
            int  oi0 = __shfl_xor(i0, m), oi1 = __shfl_xor(i1, m);
            merge2(v0, i0, v1, i1, o0, oi0, o1, oi1);
        }

        __shared__ float sv[4][2];
        __shared__ int   si[4][2];
        const int wave = t >> 6;
        if ((t & 63) == 0) {
            sv[wave][0] = v0; sv[wave][1] = v1;
            si[wave][0] = i0; si[wave][1] = i1;
        }
        __syncthreads();
        if (t == 0) {
            float a0 = sv[0][0], a1 = sv[0][1];
            int  ia0 = si[0][0], ia1 = si[0][1];
            #pragma unroll
            for (int wv = 1; wv < 4; ++wv) {
                merge2(a0, ia0, a1, ia1, sv[wv][0], si[wv][0], sv[wv][1], si[wv][1]);
            }
            ws_v[(row * SEGS + seg) * 2 + 0] = a0;
            ws_v[(row * SEGS + seg) * 2 + 1] = a1;
            ws_i[(row * SEGS + seg) * 2 + 0] = ia0;
            ws_i[(row * SEGS + seg) * 2 + 1] = ia1;
        }
    }

    // ---------------- grid-wide barrier ----------------
    cg::this_grid().sync();

    // ---------------- Phase B: blocks 0..63, one point each ----------------
    if (blk >= 64) return;
    const int pi = blk;                  // 0..63
    const int pc = pi / (Bb * Kk);
    const int pb = (pi / Kk) % Bb;
    const int pj = pi % Kk;
    const int prow = pb * 2 + pc;

    __shared__ float s_val;
    __shared__ int   s_idx;
    if (t == 0) {
        float bv0 = -INFINITY, bv1 = -INFINITY;
        int   bi0 = 0x7fffffff, bi1 = 0x7fffffff;
        for (int s2 = 0; s2 < SEGS; ++s2) {
            #pragma unroll
            for (int e = 0; e < 2; ++e) {
                const float v = ws_v[(prow * SEGS + s2) * 2 + e];
                const int   i = ws_i[(prow * SEGS + s2) * 2 + e];
                if (better(v, i, bv0, bi0)) { bv1 = bv0; bi1 = bi0; bv0 = v; bi0 = i; }
                else if (better(v, i, bv1, bi1)) { bv1 = v; bi1 = i; }
            }
        }
        s_val = (pj == 0) ? bv0 : bv1;
        s_idx = (pj == 0) ? bi0 : bi1;
    }
    __syncthreads();

    const int   idx = s_idx;
    const float val = s_val;
    const int py = idx >> 8;        // idx / W
    const int px = idx & (Ww - 1);  // idx % W

    // Output layout (flat float32, 8768 elems):
    //   [0,128)      classiferT   (64,2)
    //   [128,8320)   patchFeatDA  (64,128)
    //   [8320,8384)  labelTTrue   (64,1)
    //   [8384,8448)  labelpesudo  (64,1)
    //   [8448,8512)  provalue     (64,1)
    //   [8512,8768)  pointXY      (64,2,2) -> [px, min(px+31,255), py, min(py+31,255)]
    if (t < CF)
        out[128 + pi * CF + t] = FeatureDA[((size_t)pb * CF + t) * HWp + idx];
    if (t < 2) out[pi * 2 + t] = infeat[((size_t)pb * 2 + t) * HWp + idx];
    if (t == 0) {
        out[8320 + pi] = labelT[(size_t)pb * HWp + idx];
        out[8384 + pi] = labelTpesudo[(size_t)pb * HWp + idx];
        out[8448 + pi] = val;
        out[8512 + pi * 4 + 0] = (float)px;
        out[8512 + pi * 4 + 1] = (float)min(px + 31, 255);
        out[8512 + pi * 4 + 2] = (float)py;
        out[8512 + pi * 4 + 3] = (float)min(py + 31, 255);
    }
}

extern "C" void kernel_launch(void* const* d_in, const int* in_sizes, int n_in,
                              void* d_out, int out_size, void* d_ws, size_t ws_size,
                              hipStream_t stream) {
    const float* infeat       = (const float*)d_in[0];
    const float* labelTpesudo = (const float*)d_in[1];
    const float* labelT       = (const float*)d_in[2];
    const float* FeatureDA    = (const float*)d_in[3];
    float* out = (float*)d_out;

    float* ws_v = (float*)d_ws;                                  // 32*SEGS*2 floats
    int*   ws_i = (int*)((char*)d_ws + 32 * SEGS * 2 * sizeof(float));

    void* args[] = { (void*)&infeat, (void*)&labelTpesudo, (void*)&labelT,
                     (void*)&FeatureDA, (void*)&ws_v, (void*)&ws_i, (void*)&out };
    hipLaunchCooperativeKernel((const void*)genpixel_coop,
                               dim3(NBLK), dim3(256), args, 0, stream);
}

// Round 10
// 17.809 us; speedup vs baseline: 2.8089x; 2.8089x over previous
//
#include <hip/hip_runtime.h>
#include <math.h>

static constexpr int Bb   = 16;
static constexpr int Ww   = 256;
static constexpr int HWp  = 256 * 256;   // 65536
static constexpr int CF   = 128;
static constexpr int Kk   = 2;
static constexpr int SEGS = 8;
static constexpr int SEGLEN = HWp / SEGS; // 8192

// Strict total order matching jax.lax.top_k: value descending, index ascending on ties.
__device__ __forceinline__ bool better(float v1, int i1, float v2, int i2) {
    return (v1 > v2) || ((v1 == v2) && (i1 < i2));
}

// merge sorted pair (b0,b1) into sorted pair (a0,a1)
__device__ __forceinline__ void merge2(float& a0, int& ia0, float& a1, int& ia1,
                                       float b0, int ib0, float b1, int ib1) {
    if (better(b0, ib0, a0, ia0)) {
        float na1; int nia1;
        if (better(a0, ia0, b1, ib1)) { na1 = a0; nia1 = ia0; }
        else                          { na1 = b1; nia1 = ib1; }
        a0 = b0; ia0 = ib0; a1 = na1; ia1 = nia1;
    } else if (better(b0, ib0, a1, ia1)) {
        a1 = b0; ia1 = ib0;
    }
}

// Stage 1: per (row, seg) partial top-2 of softmax(infeat, axis=1) channel `c`.
// row = b*2 + c; 32 rows x SEGS segments. Wave butterfly + 4-wave LDS merge.
__global__ __launch_bounds__(256) void top2_partial(
    const float* __restrict__ infeat, float* __restrict__ ws_v, int* __restrict__ ws_i)
{
    const int row = blockIdx.x;        // 0..31
    const int seg = blockIdx.y;        // 0..SEGS-1
    const int b = row >> 1, c = row & 1;
    const float* x0p = infeat + (size_t)(b * 2 + 0) * HWp;
    const float* x1p = infeat + (size_t)(b * 2 + 1) * HWp;
    const int t = threadIdx.x;

    float v0 = -INFINITY, v1 = -INFINITY;
    int   i0 = 0x7fffffff, i1 = 0x7fffffff;

    const int base = seg * SEGLEN + t * 4;
    #pragma unroll
    for (int it = 0; it < SEGLEN / (256 * 4); ++it) {
        const int p = base + it * (256 * 4);
        const float4 a  = *(const float4*)(x0p + p);
        const float4 bb = *(const float4*)(x1p + p);
        const float ax[4] = {a.x, a.y, a.z, a.w};
        const float bx[4] = {bb.x, bb.y, bb.z, bb.w};
        #pragma unroll
        for (int e = 0; e < 4; ++e) {
            const float m  = fmaxf(ax[e], bx[e]);
            const float e0 = expf(ax[e] - m);
            const float e1 = expf(bx[e] - m);
            const float v  = (c == 0 ? e0 : e1) / (e0 + e1);
            const int p2 = p + e;
            if (better(v, p2, v0, i0)) { v1 = v0; i1 = i0; v0 = v; i0 = p2; }
            else if (better(v, p2, v1, i1)) { v1 = v; i1 = p2; }
        }
    }

    // 64-lane in-register butterfly
    #pragma unroll
    for (int m = 1; m < 64; m <<= 1) {
        float o0 = __shfl_xor(v0, m), o1 = __shfl_xor(v1, m);
        int  oi0 = __shfl_xor(i0, m), oi1 = __shfl_xor(i1, m);
        merge2(v0, i0, v1, i1, o0, oi0, o1, oi1);
    }

    // cross-wave: 4 wave partials -> LDS -> t0 merges
    __shared__ float sv[4][2];
    __shared__ int   si[4][2];
    const int wave = t >> 6;
    if ((t & 63) == 0) {
        sv[wave][0] = v0; sv[wave][1] = v1;
        si[wave][0] = i0; si[wave][1] = i1;
    }
    __syncthreads();
    if (t == 0) {
        float a0 = sv[0][0], a1 = sv[0][1];
        int  ia0 = si[0][0], ia1 = si[0][1];
        #pragma unroll
        for (int wv = 1; wv < 4; ++wv) {
            merge2(a0, ia0, a1, ia1, sv[wv][0], si[wv][0], sv[wv][1], si[wv][1]);
        }
        ws_v[(row * SEGS + seg) * 2 + 0] = a0;
        ws_v[(row * SEGS + seg) * 2 + 1] = a1;
        ws_i[(row * SEGS + seg) * 2 + 0] = ia0;
        ws_i[(row * SEGS + seg) * 2 + 1] = ia1;
    }
}

// Stage 2: one block per output point pi = c*B*k + b*k + j (64 points), 128 threads.
__global__ __launch_bounds__(128) void gather_out(
    const float* __restrict__ infeat,
    const float* __restrict__ labelTpesudo,
    const float* __restrict__ labelT,
    const float* __restrict__ FeatureDA,
    const float* __restrict__ ws_v, const int* __restrict__ ws_i,
    float* __restrict__ out)
{
    const int pi = blockIdx.x;           // 0..63
    const int c  = pi / (Bb * Kk);
    const int b  = (pi / Kk) % Bb;
    const int j  = pi % Kk;
    const int row = b * 2 + c;

    __shared__ float s_val;
    __shared__ int   s_idx;
    if (threadIdx.x == 0) {
        float bv0 = -INFINITY, bv1 = -INFINITY;
        int   bi0 = 0x7fffffff, bi1 = 0x7fffffff;
        for (int s2 = 0; s2 < SEGS; ++s2) {
            #pragma unroll
            for (int e = 0; e < 2; ++e) {
                const float v = ws_v[(row * SEGS + s2) * 2 + e];
                const int   i = ws_i[(row * SEGS + s2) * 2 + e];
                if (better(v, i, bv0, bi0)) { bv1 = bv0; bi1 = bi0; bv0 = v; bi0 = i; }
                else if (better(v, i, bv1, bi1)) { bv1 = v; bi1 = i; }
            }
        }
        s_val = (j == 0) ? bv0 : bv1;
        s_idx = (j == 0) ? bi0 : bi1;
    }
    __syncthreads();

    const int   idx = s_idx;
    const float val = s_val;
    const int py = idx >> 8;        // idx / W
    const int px = idx & (Ww - 1);  // idx % W
    const int t = threadIdx.x;

    // Output layout (flat float32, 8768 elems):
    //   [0,128)      classiferT   (64,2)
    //   [128,8320)   patchFeatDA  (64,128)
    //   [8320,8384)  labelTTrue   (64,1)
    //   [8384,8448)  labelpesudo  (64,1)
    //   [8448,8512)  provalue     (64,1)
    //   [8512,8768)  pointXY      (64,2,2) -> [px, min(px+31,255), py, min(py+31,255)]
    out[128 + pi * CF + t] = FeatureDA[((size_t)b * CF + t) * HWp + idx];
    if (t < 2) out[pi * 2 + t] = infeat[((size_t)b * 2 + t) * HWp + idx];
    if (t == 0) {
        out[8320 + pi] = labelT[(size_t)b * HWp + idx];
        out[8384 + pi] = labelTpesudo[(size_t)b * HWp + idx];
        out[8448 + pi] = val;
        out[8512 + pi * 4 + 0] = (float)px;
        out[8512 + pi * 4 + 1] = (float)min(px + 31, 255);
        out[8512 + pi * 4 + 2] = (float)py;
        out[8512 + pi * 4 + 3] = (float)min(py + 31, 255);
    }
}

extern "C" void kernel_launch(void* const* d_in, const int* in_sizes, int n_in,
                              void* d_out, int out_size, void* d_ws, size_t ws_size,
                              hipStream_t stream) {
    const float* infeat       = (const float*)d_in[0];
    const float* labelTpesudo = (const float*)d_in[1];
    const float* labelT       = (const float*)d_in[2];
    const float* FeatureDA    = (const float*)d_in[3];
    float* out = (float*)d_out;

    float* ws_v = (float*)d_ws;                                  // 32*SEGS*2 floats
    int*   ws_i = (int*)((char*)d_ws + 32 * SEGS * 2 * sizeof(float));

    dim3 g1(32, SEGS);
    top2_partial<<<g1, 256, 0, stream>>>(infeat, ws_v, ws_i);
    gather_out<<<64, 128, 0, stream>>>(infeat, labelTpesudo, labelT, FeatureDA,
                                       ws_v, ws_i, out);
}